// Round 3
// baseline (317.722 us; speedup 1.0000x reference)
//
#include <hip/hip_runtime.h>
#include <math.h>

#define NB 64          // batch
#define NPTS 262144    // points per batch
#define NPATCH 256
#define CHUNKS 32      // 2048 blocks total -> 8192 pts/block, 8 iters of 1024

__device__ __forceinline__ void atomAddG(float* p, float v) {
#if defined(__gfx90a__) || defined(__gfx940__) || defined(__gfx941__) || defined(__gfx942__) || defined(__gfx950__)
    unsafeAtomicAdd(p, v);
#else
    atomicAdd(p, v);
#endif
}

// ---------------- Kernel A: segment reduction over points ----------------
// Block-phased LDS staging (barriered, race-free). All global loads are
// contiguous 1KB-per-wave dwordx4. sums planar: [0)=birth,[16384)=pers,[32768)=count
__global__ __launch_bounds__(256) void seg_reduce(
    const float* __restrict__ pers, const int* __restrict__ pix,
    float* __restrict__ sums)
{
    __shared__ float accB[NPATCH], accP[NPATCH], accC[NPATCH];
    __shared__ float4 SP[768];              // 1024 pts * 3 floats = 12KB
    __shared__ unsigned short SPAT[1024];   // pat | (pix_nz<<8), 2KB

    const int tid = threadIdx.x;
    accB[tid] = 0.f; accP[tid] = 0.f; accC[tid] = 0.f;

    const int b = blockIdx.y;
    const long long base = (long long)b * NPTS + (long long)blockIdx.x * 8192;

    for (int it = 0; it < 8; ++it) {
        const long long p0 = base + it * 1024;
        const float4* srcp = (const float4*)(pers + p0 * 3);
        const int4*   srcq = (const int4*)(pix + p0 * 2);
        // Prefetch into registers BEFORE the barrier: overlaps HBM latency
        // with the previous tile's processing; registers are private (no race).
        float4 r0 = srcp[tid];
        float4 r1 = srcp[tid + 256];
        float4 r2 = srcp[tid + 512];
        int4   q0 = srcq[tid];
        int4   q1 = srcq[tid + 256];

        __syncthreads();   // previous tile's LDS reads done before overwrite
        SP[tid]       = r0;
        SP[tid + 256] = r1;
        SP[tid + 512] = r2;
        auto mkpat = [](int x, int y) -> unsigned {
            int px = min(max(x, 0) / 14, 15);
            int py = min(max(y, 0) / 14, 15);
            unsigned pat = (unsigned)((py << 4) | px);
            if ((x | y) != 0) pat |= 256u;
            return pat;
        };
        // q0 = {x,y} of points 2*tid, 2*tid+1 ; q1 = points 512+2*tid, 513+2*tid
        ((unsigned*)SPAT)[tid]       = mkpat(q0.x, q0.y) | (mkpat(q0.z, q0.w) << 16);
        ((unsigned*)SPAT)[tid + 256] = mkpat(q1.x, q1.y) | (mkpat(q1.z, q1.w) << 16);
        __syncthreads();   // staged data visible to whole block

        const float* SF = (const float*)SP;
#pragma unroll
        for (int k = 0; k < 4; ++k) {
            const int p = tid + k * 256;               // stride-3 dwords: 2-way bank = free
            const float bx = SF[p * 3 + 0];
            const float by = SF[p * 3 + 1];
            const float bz = SF[p * 3 + 2];
            const unsigned s = SPAT[p];
            const int pat = (int)(s & 255u);
            const bool nz = (s & 256u) || (bx != 0.f) || (by != 0.f) || (bz != 0.f);
            // invalid rows have bx==bz==0 exactly -> unconditional adds safe
            atomicAdd(&accB[pat], bx);
            atomicAdd(&accP[pat], bz);
            atomicAdd(&accC[pat], nz ? 1.f : 0.f);
        }
    }
    __syncthreads();

    const int row = b * NPATCH + tid;
    atomAddG(&sums[row],         accB[tid]);
    atomAddG(&sums[16384 + row], accP[tid]);
    atomAddG(&sums[32768 + row], accC[tid]);
}

// ---------------- Kernel B: precompute base/Mb/Mp (+ zero sums) ----------------
__global__ __launch_bounds__(256) void precompute(
    const float* __restrict__ sp,
    const float* __restrict__ bw2, const float* __restrict__ bb2,
    const float* __restrict__ pw2, const float* __restrict__ pb2,
    const float* __restrict__ fw, const float* __restrict__ fb,
    float* __restrict__ baseT, float* __restrict__ Mb, float* __restrict__ Mp,
    float* __restrict__ sums)
{
    const int bid = blockIdx.x;
    const int d = threadIdx.x;
    {
        int i = bid * 256 + d;
        if (i < 49152) sums[i] = 0.f;
    }
    if (bid < 256) {
        __shared__ float spl[128];
        if (d < 128) spl[d] = sp[bid * 128 + d];
        __syncthreads();
        float a = fb[d];
        for (int i = 0; i < 64; ++i) a += bb2[i] * fw[(128 + i) * 256 + d];
        for (int i = 0; i < 64; ++i) a += pb2[i] * fw[(192 + i) * 256 + d];
        for (int k = 0; k < 128; ++k) a += spl[k] * fw[k * 256 + d];
        baseT[bid * 256 + d] = a;
    } else if (bid < 320) {
        const int i = bid - 256;
        float a = 0.f;
        for (int j = 0; j < 64; ++j) a += bw2[i * 64 + j] * fw[(128 + j) * 256 + d];
        Mb[i * 256 + d] = a;
    } else if (bid < 384) {
        const int i = bid - 320;
        float a = 0.f;
        for (int j = 0; j < 64; ++j) a += pw2[i * 64 + j] * fw[(192 + j) * 256 + d];
        Mp[i * 256 + d] = a;
    }
}

// ---------------- Kernel C: h = base + h1b@Mb + h1p@Mp, LN, tanh ----------------
__global__ __launch_bounds__(256) void fuse(
    const float* __restrict__ sums,
    const float* __restrict__ bw1, const float* __restrict__ bb1,
    const float* __restrict__ pw1, const float* __restrict__ pb1,
    const float* __restrict__ baseT,
    const float* __restrict__ Mb, const float* __restrict__ Mp,
    const float* __restrict__ lnw, const float* __restrict__ lnb,
    float* __restrict__ out)
{
    __shared__ float avg[32][2];
    __shared__ float h1[64][32][2];
    const int tid = threadIdx.x;
    const int r0 = blockIdx.x * 32;

    if (tid < 32) {
        int row = r0 + tid;
        float bs = sums[row];
        float ps = sums[16384 + row];
        float cn = sums[32768 + row];
        float inv = (cn > 0.f) ? 1.f / cn : 0.f;
        avg[tid][0] = bs * inv;
        avg[tid][1] = ps * inv;
    }
    __syncthreads();

    for (int idx = tid; idx < 64 * 32; idx += 256) {
        int k = idx >> 5, r = idx & 31;
        h1[k][r][0] = fmaxf(avg[r][0] * bw1[k] + bb1[k], 0.f);
        h1[k][r][1] = fmaxf(avg[r][1] * pw1[k] + pb1[k], 0.f);
    }
    __syncthreads();

    const int dg = tid & 63;
    const int rg = tid >> 6;
    const int d0 = dg * 4;
    const int row0 = r0 + rg * 8;

    float4 acc[8];
#pragma unroll
    for (int rr = 0; rr < 8; ++rr)
        acc[rr] = *(const float4*)(baseT + ((row0 + rr) & 255) * 256 + d0);

    for (int k = 0; k < 64; ++k) {
        const float4 mb = *(const float4*)(Mb + k * 256 + d0);
        const float4 mp = *(const float4*)(Mp + k * 256 + d0);
#pragma unroll
        for (int rr = 0; rr < 8; rr += 2) {
            const float4 h = *(const float4*)(&h1[k][rg * 8 + rr][0]);
            acc[rr].x   += h.x * mb.x + h.y * mp.x;
            acc[rr].y   += h.x * mb.y + h.y * mp.y;
            acc[rr].z   += h.x * mb.z + h.y * mp.z;
            acc[rr].w   += h.x * mb.w + h.y * mp.w;
            acc[rr+1].x += h.z * mb.x + h.w * mp.x;
            acc[rr+1].y += h.z * mb.y + h.w * mp.y;
            acc[rr+1].z += h.z * mb.z + h.w * mp.z;
            acc[rr+1].w += h.z * mb.w + h.w * mp.w;
        }
    }

    const float4 lw = *(const float4*)(lnw + d0);
    const float4 lb = *(const float4*)(lnb + d0);

#pragma unroll
    for (int rr = 0; rr < 8; ++rr) {
        float4 v = acc[rr];
        float s = v.x + v.y + v.z + v.w;
        float q = v.x * v.x + v.y * v.y + v.z * v.z + v.w * v.w;
#pragma unroll
        for (int m = 1; m < 64; m <<= 1) {
            s += __shfl_xor(s, m);
            q += __shfl_xor(q, m);
        }
        float mu = s * (1.f / 256.f);
        float var = q * (1.f / 256.f) - mu * mu;
        float rstd = rsqrtf(var + 1e-5f);
        float4 o;
        o.x = tanhf((v.x - mu) * rstd * lw.x + lb.x);
        o.y = tanhf((v.y - mu) * rstd * lw.y + lb.y);
        o.z = tanhf((v.z - mu) * rstd * lw.z + lb.z);
        o.w = tanhf((v.w - mu) * rstd * lw.w + lb.w);
        *(float4*)(out + (long long)(row0 + rr) * 256 + d0) = o;
    }
}

extern "C" void kernel_launch(void* const* d_in, const int* in_sizes, int n_in,
                              void* d_out, int out_size, void* d_ws, size_t ws_size,
                              hipStream_t stream) {
    const float* pers = (const float*)d_in[1];
    const int*   pix  = (const int*)d_in[2];
    const float* sp   = (const float*)d_in[3];
    const float* bw1  = (const float*)d_in[4];
    const float* bb1  = (const float*)d_in[5];
    const float* bw2  = (const float*)d_in[6];
    const float* bb2  = (const float*)d_in[7];
    const float* pw1  = (const float*)d_in[8];
    const float* pb1  = (const float*)d_in[9];
    const float* pw2  = (const float*)d_in[10];
    const float* pb2  = (const float*)d_in[11];
    const float* fw   = (const float*)d_in[12];
    const float* fb   = (const float*)d_in[13];
    const float* lnw  = (const float*)d_in[14];
    const float* lnb  = (const float*)d_in[15];
    float* out = (float*)d_out;

    float* sums  = (float*)d_ws;             // 49152 floats (planar B/P/C)
    float* baseT = sums + 49152;             // 256*256
    float* Mb    = baseT + 65536;            // 64*256
    float* Mp    = Mb + 16384;               // 64*256

    precompute<<<384, 256, 0, stream>>>(sp, bw2, bb2, pw2, pb2, fw, fb, baseT, Mb, Mp, sums);
    seg_reduce<<<dim3(CHUNKS, NB), 256, 0, stream>>>(pers, pix, sums);
    fuse<<<512, 256, 0, stream>>>(sums, bw1, bb1, pw1, pb1, baseT, Mb, Mp, lnw, lnb, out);
}

// Round 4
// 116.529 us; speedup vs baseline: 2.7266x; 2.7266x over previous
//
#include <hip/hip_runtime.h>
#include <math.h>

#define NB 64          // batch
#define NPTS 262144    // points per batch
#define NPATCH 256
#define CHUNKS 32      // 2048 blocks -> 8192 pts/block, 8 quads/thread

// u64 packing: [0:25) bxq  (Σ round((bx+8)*256), ≤2^25 per bin)
//              [25:50) bzq (Σ round((bz+8)*256))
//              [50:64) count
#define MASK25 0x1FFFFFFu

// ---------------- Kernel A: segment reduction, ONE ds_add_u64 per point ----------------
__global__ __launch_bounds__(256) void seg_reduce(
    const float* __restrict__ pers, const int* __restrict__ pix,
    unsigned long long* __restrict__ sums)
{
    __shared__ unsigned long long acc[NPATCH];
    const int tid = threadIdx.x;
    acc[tid] = 0ull;
    __syncthreads();

    const int b = blockIdx.y;
    const long long base = (long long)b * NPTS + (long long)blockIdx.x * 8192 + tid * 4;

    auto dopoint = [&](float bx, float by, float bz, int x, int y) {
        const int px = min(max(x, 0) / 14, 15);
        const int py = min(max(y, 0) / 14, 15);
        const int pat = py * 16 + px;
        const bool valid = ((x | y) != 0) | (bx != 0.f) | (by != 0.f) | (bz != 0.f);
        const unsigned bxq = valid ? (unsigned)__float2int_rn((bx + 8.f) * 256.f) : 0u;
        const unsigned bzq = valid ? (unsigned)__float2int_rn((bz + 8.f) * 256.f) : 0u;
        const unsigned long long payload =
            (unsigned long long)bxq |
            ((unsigned long long)bzq << 25) |
            ((unsigned long long)(valid ? 1u : 0u) << 50);
        atomicAdd(&acc[pat], payload);
    };

    const float4* pc = (const float4*)(pers + base * 3);
    const int4*   pq = (const int4*)(pix + base * 2);
    // quad 'it' starts at float4 index it*768 (pers) / int4 index it*512 (pix)

    float4 c0 = pc[0], c1 = pc[1], c2 = pc[2];
    int4   q0 = pq[0], q1 = pq[1];
#pragma unroll
    for (int it = 0; it < 8; ++it) {
        float4 n0, n1, n2; int4 m0, m1;
        if (it < 7) {   // prefetch next quad before this quad's atomics
            n0 = pc[(it + 1) * 768 + 0];
            n1 = pc[(it + 1) * 768 + 1];
            n2 = pc[(it + 1) * 768 + 2];
            m0 = pq[(it + 1) * 512 + 0];
            m1 = pq[(it + 1) * 512 + 1];
        }
        dopoint(c0.x, c0.y, c0.z, q0.x, q0.y);
        dopoint(c0.w, c1.x, c1.y, q0.z, q0.w);
        dopoint(c1.z, c1.w, c2.x, q1.x, q1.y);
        dopoint(c2.y, c2.z, c2.w, q1.z, q1.w);
        c0 = n0; c1 = n1; c2 = n2; q0 = m0; q1 = m1;
    }
    __syncthreads();

    atomicAdd(&sums[(long long)b * NPATCH + tid], acc[tid]);
}

// ---------------- Kernel B: precompute base/Mb/Mp (+ zero sums) ----------------
__global__ __launch_bounds__(256) void precompute(
    const float* __restrict__ sp,
    const float* __restrict__ bw2, const float* __restrict__ bb2,
    const float* __restrict__ pw2, const float* __restrict__ pb2,
    const float* __restrict__ fw, const float* __restrict__ fb,
    float* __restrict__ baseT, float* __restrict__ Mb, float* __restrict__ Mp,
    unsigned* __restrict__ sums32)
{
    const int bid = blockIdx.x;
    const int d = threadIdx.x;
    {   // zero the 16384 u64 accumulators (= 32768 u32)
        int i = bid * 256 + d;
        if (i < 32768) sums32[i] = 0u;
    }
    if (bid < 256) {
        __shared__ float spl[128];
        if (d < 128) spl[d] = sp[bid * 128 + d];
        __syncthreads();
        float a = fb[d];
        for (int i = 0; i < 64; ++i) a += bb2[i] * fw[(128 + i) * 256 + d];
        for (int i = 0; i < 64; ++i) a += pb2[i] * fw[(192 + i) * 256 + d];
        for (int k = 0; k < 128; ++k) a += spl[k] * fw[k * 256 + d];
        baseT[bid * 256 + d] = a;
    } else if (bid < 320) {
        const int i = bid - 256;
        float a = 0.f;
        for (int j = 0; j < 64; ++j) a += bw2[i * 64 + j] * fw[(128 + j) * 256 + d];
        Mb[i * 256 + d] = a;
    } else if (bid < 384) {
        const int i = bid - 320;
        float a = 0.f;
        for (int j = 0; j < 64; ++j) a += pw2[i * 64 + j] * fw[(192 + j) * 256 + d];
        Mp[i * 256 + d] = a;
    }
}

// ---------------- Kernel C: h = base + h1b@Mb + h1p@Mp, LN, tanh ----------------
__global__ __launch_bounds__(256) void fuse(
    const unsigned long long* __restrict__ sums,
    const float* __restrict__ bw1, const float* __restrict__ bb1,
    const float* __restrict__ pw1, const float* __restrict__ pb1,
    const float* __restrict__ baseT,
    const float* __restrict__ Mb, const float* __restrict__ Mp,
    const float* __restrict__ lnw, const float* __restrict__ lnb,
    float* __restrict__ out)
{
    __shared__ float avg[32][2];
    __shared__ float h1[64][32][2];
    const int tid = threadIdx.x;
    const int r0 = blockIdx.x * 32;

    if (tid < 32) {
        unsigned long long q = sums[r0 + tid];
        float cn = (float)(unsigned)(q >> 50);
        float bs = (float)(unsigned)(q & MASK25) * (1.f / 256.f) - 8.f * cn;
        float ps = (float)(unsigned)((q >> 25) & MASK25) * (1.f / 256.f) - 8.f * cn;
        float inv = (cn > 0.f) ? 1.f / cn : 0.f;
        avg[tid][0] = bs * inv;
        avg[tid][1] = ps * inv;
    }
    __syncthreads();

    for (int idx = tid; idx < 64 * 32; idx += 256) {
        int k = idx >> 5, r = idx & 31;
        h1[k][r][0] = fmaxf(avg[r][0] * bw1[k] + bb1[k], 0.f);
        h1[k][r][1] = fmaxf(avg[r][1] * pw1[k] + pb1[k], 0.f);
    }
    __syncthreads();

    const int dg = tid & 63;
    const int rg = tid >> 6;
    const int d0 = dg * 4;
    const int row0 = r0 + rg * 8;

    float4 acc[8];
#pragma unroll
    for (int rr = 0; rr < 8; ++rr)
        acc[rr] = *(const float4*)(baseT + ((row0 + rr) & 255) * 256 + d0);

    for (int k = 0; k < 64; ++k) {
        const float4 mb = *(const float4*)(Mb + k * 256 + d0);
        const float4 mp = *(const float4*)(Mp + k * 256 + d0);
#pragma unroll
        for (int rr = 0; rr < 8; rr += 2) {
            const float4 h = *(const float4*)(&h1[k][rg * 8 + rr][0]);
            acc[rr].x   += h.x * mb.x + h.y * mp.x;
            acc[rr].y   += h.x * mb.y + h.y * mp.y;
            acc[rr].z   += h.x * mb.z + h.y * mp.z;
            acc[rr].w   += h.x * mb.w + h.y * mp.w;
            acc[rr+1].x += h.z * mb.x + h.w * mp.x;
            acc[rr+1].y += h.z * mb.y + h.w * mp.y;
            acc[rr+1].z += h.z * mb.z + h.w * mp.z;
            acc[rr+1].w += h.z * mb.w + h.w * mp.w;
        }
    }

    const float4 lw = *(const float4*)(lnw + d0);
    const float4 lb = *(const float4*)(lnb + d0);

#pragma unroll
    for (int rr = 0; rr < 8; ++rr) {
        float4 v = acc[rr];
        float s = v.x + v.y + v.z + v.w;
        float q = v.x * v.x + v.y * v.y + v.z * v.z + v.w * v.w;
#pragma unroll
        for (int m = 1; m < 64; m <<= 1) {
            s += __shfl_xor(s, m);
            q += __shfl_xor(q, m);
        }
        float mu = s * (1.f / 256.f);
        float var = q * (1.f / 256.f) - mu * mu;
        float rstd = rsqrtf(var + 1e-5f);
        float4 o;
        o.x = tanhf((v.x - mu) * rstd * lw.x + lb.x);
        o.y = tanhf((v.y - mu) * rstd * lw.y + lb.y);
        o.z = tanhf((v.z - mu) * rstd * lw.z + lb.z);
        o.w = tanhf((v.w - mu) * rstd * lw.w + lb.w);
        *(float4*)(out + (long long)(row0 + rr) * 256 + d0) = o;
    }
}

extern "C" void kernel_launch(void* const* d_in, const int* in_sizes, int n_in,
                              void* d_out, int out_size, void* d_ws, size_t ws_size,
                              hipStream_t stream) {
    const float* pers = (const float*)d_in[1];
    const int*   pix  = (const int*)d_in[2];
    const float* sp   = (const float*)d_in[3];
    const float* bw1  = (const float*)d_in[4];
    const float* bb1  = (const float*)d_in[5];
    const float* bw2  = (const float*)d_in[6];
    const float* bb2  = (const float*)d_in[7];
    const float* pw1  = (const float*)d_in[8];
    const float* pb1  = (const float*)d_in[9];
    const float* pw2  = (const float*)d_in[10];
    const float* pb2  = (const float*)d_in[11];
    const float* fw   = (const float*)d_in[12];
    const float* fb   = (const float*)d_in[13];
    const float* lnw  = (const float*)d_in[14];
    const float* lnb  = (const float*)d_in[15];
    float* out = (float*)d_out;

    unsigned long long* sums = (unsigned long long*)d_ws;   // 16384 u64 = 128KB
    float* baseT = (float*)d_ws + 32768;                    // 256*256
    float* Mb    = baseT + 65536;                           // 64*256
    float* Mp    = Mb + 16384;                              // 64*256

    precompute<<<384, 256, 0, stream>>>(sp, bw2, bb2, pw2, pb2, fw, fb,
                                        baseT, Mb, Mp, (unsigned*)sums);
    seg_reduce<<<dim3(CHUNKS, NB), 256, 0, stream>>>(pers, pix, sums);
    fuse<<<512, 256, 0, stream>>>(sums, bw1, bb1, pw1, pb1, baseT, Mb, Mp, lnw, lnb, out);
}